// Round 1
// baseline (92.659 us; speedup 1.0000x reference)
//
#include <hip/hip_runtime.h>

// Problem constants (from reference setup_inputs): B=8, C=12, Ny=Nx=512, k=3 SAME pad=1.
#define NYv 512
#define NXv 512
#define CCv 12

// Tile: 256 px wide (64 threads x float4) x 8 rows tall -> 512 threads/block.
__global__ __launch_bounds__(512)
void momentum_kernel(const float* __restrict__ Rq_re,
                     const float* __restrict__ Rq_im,
                     const float* __restrict__ Dq_re,
                     const float* __restrict__ Dq_im,
                     const float* __restrict__ cache_re,
                     const float* __restrict__ cache_im,
                     const float* __restrict__ filt,
                     float* __restrict__ out)
{
    __shared__ float sf[CCv * 9];
    const int tid = threadIdx.y * 64 + threadIdx.x;
    if (tid < CCv * 9) sf[tid] = filt[tid];
    __syncthreads();

    const int b  = blockIdx.z;
    const int y  = blockIdx.y * 8 + threadIdx.y;
    const int x0 = blockIdx.x * 256 + threadIdx.x * 4;

    // ---- pointwise part: Rq + Dq (each (B,1,NY,NX)) ----
    const int base1 = (b * NYv + y) * NXv + x0;
    const float4 a0 = *(const float4*)(Rq_re + base1);
    const float4 a1 = *(const float4*)(Dq_re + base1);
    const float4 b0 = *(const float4*)(Rq_im + base1);
    const float4 b1 = *(const float4*)(Dq_im + base1);

    float4 acc_re = make_float4(a0.x + a1.x, a0.y + a1.y, a0.z + a1.z, a0.w + a1.w);
    float4 acc_im = make_float4(b0.x + b1.x, b0.y + b1.y, b0.z + b1.z, b0.w + b1.w);

    const bool has_l = (x0 > 0);
    const bool has_r = (x0 + 4 < NXv);

    // ---- channel-reduced depthwise 3x3 conv over cache_re / cache_im ----
    #pragma unroll 4
    for (int c = 0; c < CCv; ++c) {
        const float* pre = cache_re + ((b * CCv + c) * NYv) * NXv + x0;
        const float* pim = cache_im + ((b * CCv + c) * NYv) * NXv + x0;
        #pragma unroll
        for (int dy = 0; dy < 3; ++dy) {
            const int yy = y + dy - 1;
            if (yy < 0 || yy >= NYv) continue;   // SAME pad=1: zero contribution
            const float w0 = sf[c * 9 + dy * 3 + 0];
            const float w1 = sf[c * 9 + dy * 3 + 1];
            const float w2 = sf[c * 9 + dy * 3 + 2];

            const float* rowr = pre + yy * NXv;
            const float4 v  = *(const float4*)rowr;
            const float  l  = has_l ? rowr[-1] : 0.f;
            const float  r  = has_r ? rowr[4]  : 0.f;
            acc_re.x += w0 * l   + w1 * v.x + w2 * v.y;
            acc_re.y += w0 * v.x + w1 * v.y + w2 * v.z;
            acc_re.z += w0 * v.y + w1 * v.z + w2 * v.w;
            acc_re.w += w0 * v.z + w1 * v.w + w2 * r;

            const float* rowi = pim + yy * NXv;
            const float4 vi = *(const float4*)rowi;
            const float  li = has_l ? rowi[-1] : 0.f;
            const float  ri = has_r ? rowi[4]  : 0.f;
            acc_im.x += w0 * li   + w1 * vi.x + w2 * vi.y;
            acc_im.y += w0 * vi.x + w1 * vi.y + w2 * vi.z;
            acc_im.z += w0 * vi.y + w1 * vi.z + w2 * vi.w;
            acc_im.w += w0 * vi.z + w1 * vi.w + w2 * ri;
        }
    }

    // ---- output (B, 2, NY, NX): channel 0 = re, channel 1 = im ----
    float* o_re = out + ((b * 2 + 0) * NYv + y) * NXv + x0;
    float* o_im = out + ((b * 2 + 1) * NYv + y) * NXv + x0;
    *(float4*)o_re = acc_re;
    *(float4*)o_im = acc_im;
}

extern "C" void kernel_launch(void* const* d_in, const int* in_sizes, int n_in,
                              void* d_out, int out_size, void* d_ws, size_t ws_size,
                              hipStream_t stream) {
    const float* Rq_re    = (const float*)d_in[0];
    const float* Rq_im    = (const float*)d_in[1];
    const float* Dq_re    = (const float*)d_in[2];
    const float* Dq_im    = (const float*)d_in[3];
    const float* cache_re = (const float*)d_in[4];
    const float* cache_im = (const float*)d_in[5];
    const float* filt     = (const float*)d_in[6];
    float* out = (float*)d_out;

    const int B = in_sizes[0] / (NYv * NXv);   // = 8

    dim3 block(64, 8);
    dim3 grid(NXv / 256, NYv / 8, B);
    momentum_kernel<<<grid, block, 0, stream>>>(Rq_re, Rq_im, Dq_re, Dq_im,
                                                cache_re, cache_im, filt, out);
}

// Round 2
// 73.985 us; speedup vs baseline: 1.2524x; 1.2524x over previous
//
#include <hip/hip_runtime.h>

// B=8, C=12, Ny=Nx=512, 3x3 depthwise conv SAME pad=1, channel-reduced, + Rq + Dq.
#define NY 512
#define NX 512
#define CC 12
#define ROWS 4   // output rows per thread

struct Row { float4 v; float l, r; };

// Accumulate one plane (6 input rows -> 4 output rows) for one channel.
__device__ __forceinline__
void conv_plane(const float* __restrict__ p,   // points at (y0-1, x0) of this plane
                const float w[9], int y0, bool has_l, bool has_r,
                float4 acc[ROWS])
{
    Row rw[ROWS + 2];
    #pragma unroll
    for (int j = 0; j < ROWS + 2; ++j) {
        const int yy = y0 - 1 + j;
        const float* row = p + j * NX;
        if (0 <= yy && yy < NY) {                 // wave-uniform branch
            rw[j].v = *(const float4*)row;
            rw[j].l = has_l ? row[-1] : 0.f;
            rw[j].r = has_r ? row[4]  : 0.f;
        } else {
            rw[j].v = make_float4(0.f, 0.f, 0.f, 0.f);
            rw[j].l = 0.f; rw[j].r = 0.f;
        }
    }
    #pragma unroll
    for (int r = 0; r < ROWS; ++r) {
        #pragma unroll
        for (int t = 0; t < 3; ++t) {             // dy = t-1, input row index j = r+t
            const int   j  = r + t;
            const float w0 = w[t*3+0], w1 = w[t*3+1], w2 = w[t*3+2];
            acc[r].x += w0*rw[j].l   + w1*rw[j].v.x + w2*rw[j].v.y;
            acc[r].y += w0*rw[j].v.x + w1*rw[j].v.y + w2*rw[j].v.z;
            acc[r].z += w0*rw[j].v.y + w1*rw[j].v.z + w2*rw[j].v.w;
            acc[r].w += w0*rw[j].v.z + w1*rw[j].v.w + w2*rw[j].r;
        }
    }
}

// Block (64,4) = 256 threads. Tile: 256 px wide x 16 rows. Grid (2, 32, 8) = 512 blocks.
__global__ __launch_bounds__(256)
void momentum_kernel(const float* __restrict__ Rq_re,
                     const float* __restrict__ Rq_im,
                     const float* __restrict__ Dq_re,
                     const float* __restrict__ Dq_im,
                     const float* __restrict__ cache_re,
                     const float* __restrict__ cache_im,
                     const float* __restrict__ filt,
                     float* __restrict__ out)
{
    __shared__ float sf[CC * 9];
    const int tid = threadIdx.y * 64 + threadIdx.x;
    if (tid < CC * 9) sf[tid] = filt[tid];
    __syncthreads();

    const int b  = blockIdx.z;
    const int y0 = blockIdx.y * (4 * ROWS) + threadIdx.y * ROWS;
    const int x0 = blockIdx.x * 256 + threadIdx.x * 4;
    const bool has_l = (x0 > 0);
    const bool has_r = (x0 + 4 < NX);

    // ---- pointwise: Rq + Dq ----
    float4 acc_re[ROWS], acc_im[ROWS];
    #pragma unroll
    for (int r = 0; r < ROWS; ++r) {
        const int idx = (b * NY + y0 + r) * NX + x0;
        const float4 a  = *(const float4*)(Rq_re + idx);
        const float4 d  = *(const float4*)(Dq_re + idx);
        const float4 ai = *(const float4*)(Rq_im + idx);
        const float4 di = *(const float4*)(Dq_im + idx);
        acc_re[r] = make_float4(a.x+d.x,  a.y+d.y,  a.z+d.z,  a.w+d.w);
        acc_im[r] = make_float4(ai.x+di.x, ai.y+di.y, ai.z+di.z, ai.w+di.w);
    }

    // ---- channel-reduced depthwise 3x3 ----
    for (int c = 0; c < CC; ++c) {
        float w[9];
        #pragma unroll
        for (int i = 0; i < 9; ++i) w[i] = sf[c * 9 + i];

        const float* pr = cache_re + (((b * CC + c) * NY) + y0 - 1) * NX + x0;
        const float* pi = cache_im + (((b * CC + c) * NY) + y0 - 1) * NX + x0;
        conv_plane(pr, w, y0, has_l, has_r, acc_re);
        conv_plane(pi, w, y0, has_l, has_r, acc_im);
    }

    // ---- store (B, 2, NY, NX) ----
    #pragma unroll
    for (int r = 0; r < ROWS; ++r) {
        float* o_re = out + ((b * 2 + 0) * NY + y0 + r) * NX + x0;
        float* o_im = out + ((b * 2 + 1) * NY + y0 + r) * NX + x0;
        *(float4*)o_re = acc_re[r];
        *(float4*)o_im = acc_im[r];
    }
}

extern "C" void kernel_launch(void* const* d_in, const int* in_sizes, int n_in,
                              void* d_out, int out_size, void* d_ws, size_t ws_size,
                              hipStream_t stream) {
    const float* Rq_re    = (const float*)d_in[0];
    const float* Rq_im    = (const float*)d_in[1];
    const float* Dq_re    = (const float*)d_in[2];
    const float* Dq_im    = (const float*)d_in[3];
    const float* cache_re = (const float*)d_in[4];
    const float* cache_im = (const float*)d_in[5];
    const float* filt     = (const float*)d_in[6];
    float* out = (float*)d_out;

    const int B = in_sizes[0] / (NY * NX);   // = 8

    dim3 block(64, 4);
    dim3 grid(NX / 256, NY / (4 * ROWS), B);
    momentum_kernel<<<grid, block, 0, stream>>>(Rq_re, Rq_im, Dq_re, Dq_im,
                                                cache_re, cache_im, filt, out);
}

// Round 3
// 60.708 us; speedup vs baseline: 1.5263x; 1.2187x over previous
//
#include <hip/hip_runtime.h>

// B=8, C=12, Ny=Nx=512, 3x3 depthwise conv SAME pad=1, channel-reduced, + Rq + Dq.
#define NY 512
#define NX 512
#define CC 12

// One plane-row contribution: v0,v1 = 8 px of the input row held by this lane.
// x-halo via cross-lane shuffles (no memory ops). Weights pre-masked for y-edges.
__device__ __forceinline__ void row_conv(const float4& v0, const float4& v1,
                                         float w0, float w1, float w2, int lane,
                                         float4& a0, float4& a1)
{
    float l0 = __shfl_up(v1.w, 1);    // px 8i-1 from lane i-1
    if (lane == 0) l0 = 0.f;          // image left edge (x=0)
    float r1 = __shfl_down(v0.x, 1);  // px 8i+8 from lane i+1
    if (lane == 63) r1 = 0.f;         // image right edge (x=511)

    a0.x += w0*l0   + w1*v0.x + w2*v0.y;
    a0.y += w0*v0.x + w1*v0.y + w2*v0.z;
    a0.z += w0*v0.y + w1*v0.z + w2*v0.w;
    a0.w += w0*v0.z + w1*v0.w + w2*v1.x;
    a1.x += w0*v0.w + w1*v1.x + w2*v1.y;
    a1.y += w0*v1.x + w1*v1.y + w2*v1.z;
    a1.z += w0*v1.y + w1*v1.z + w2*v1.w;
    a1.w += w0*v1.z + w1*v1.w + w2*r1;
}

// Block: 256 threads = 4 waves; each wave owns one full output row (512 px, re+im).
// Grid: (NY/4, B) = (128, 8) = 1024 blocks -> 4096 waves -> 16 waves/CU.
__global__ __launch_bounds__(256, 4)
void momentum_kernel(const float* __restrict__ Rq_re, const float* __restrict__ Rq_im,
                     const float* __restrict__ Dq_re, const float* __restrict__ Dq_im,
                     const float* __restrict__ cache_re, const float* __restrict__ cache_im,
                     const float* __restrict__ filt, float* __restrict__ out)
{
    const int tid  = threadIdx.x;
    const int wave = tid >> 6;
    const int lane = tid & 63;
    const int b    = blockIdx.y;
    const int y    = blockIdx.x * 4 + wave;
    const int x0   = lane * 8;

    // y-halo: clamped row index + 0/1 weight mask (wave-uniform, branch-free loads)
    const int   ym1   = (y > 0)      ? y - 1 : 0;
    const int   yp1   = (y < NY - 1) ? y + 1 : NY - 1;
    const float m_top = (y > 0)      ? 1.f : 0.f;
    const float m_bot = (y < NY - 1) ? 1.f : 0.f;

    const int off_t = ym1 * NX + x0;
    const int off_m = y   * NX + x0;
    const int off_b = yp1 * NX + x0;

    // ---- pointwise: Rq + Dq (8 independent loads, one batch) ----
    float4 ar0, ar1, ai0, ai1;
    {
        const int base = (b * NY + y) * NX + x0;
        const float4 q0 = *(const float4*)(Rq_re + base);
        const float4 q1 = *(const float4*)(Rq_re + base + 4);
        const float4 d0 = *(const float4*)(Dq_re + base);
        const float4 d1 = *(const float4*)(Dq_re + base + 4);
        const float4 u0 = *(const float4*)(Rq_im + base);
        const float4 u1 = *(const float4*)(Rq_im + base + 4);
        const float4 e0 = *(const float4*)(Dq_im + base);
        const float4 e1 = *(const float4*)(Dq_im + base + 4);
        ar0 = make_float4(q0.x + d0.x, q0.y + d0.y, q0.z + d0.z, q0.w + d0.w);
        ar1 = make_float4(q1.x + d1.x, q1.y + d1.y, q1.z + d1.z, q1.w + d1.w);
        ai0 = make_float4(u0.x + e0.x, u0.y + e0.y, u0.z + e0.z, u0.w + e0.w);
        ai1 = make_float4(u1.x + e1.x, u1.y + e1.y, u1.z + e1.z, u1.w + e1.w);
    }

    // ---- channel-reduced depthwise 3x3: 12 unconditional loads per channel ----
    for (int c = 0; c < CC; ++c) {
        const float* cr = cache_re + (size_t)(b * CC + c) * (NY * NX);
        const float* ci = cache_im + (size_t)(b * CC + c) * (NY * NX);

        const float4 rt0 = *(const float4*)(cr + off_t);
        const float4 rt1 = *(const float4*)(cr + off_t + 4);
        const float4 rm0 = *(const float4*)(cr + off_m);
        const float4 rm1 = *(const float4*)(cr + off_m + 4);
        const float4 rb0 = *(const float4*)(cr + off_b);
        const float4 rb1 = *(const float4*)(cr + off_b + 4);
        const float4 it0 = *(const float4*)(ci + off_t);
        const float4 it1 = *(const float4*)(ci + off_t + 4);
        const float4 im0 = *(const float4*)(ci + off_m);
        const float4 im1 = *(const float4*)(ci + off_m + 4);
        const float4 ib0 = *(const float4*)(ci + off_b);
        const float4 ib1 = *(const float4*)(ci + off_b + 4);

        const float* f = filt + c * 9;           // uniform -> s_load path
        const float w00 = f[0] * m_top, w01 = f[1] * m_top, w02 = f[2] * m_top;
        const float w10 = f[3],         w11 = f[4],         w12 = f[5];
        const float w20 = f[6] * m_bot, w21 = f[7] * m_bot, w22 = f[8] * m_bot;

        row_conv(rt0, rt1, w00, w01, w02, lane, ar0, ar1);
        row_conv(rm0, rm1, w10, w11, w12, lane, ar0, ar1);
        row_conv(rb0, rb1, w20, w21, w22, lane, ar0, ar1);
        row_conv(it0, it1, w00, w01, w02, lane, ai0, ai1);
        row_conv(im0, im1, w10, w11, w12, lane, ai0, ai1);
        row_conv(ib0, ib1, w20, w21, w22, lane, ai0, ai1);
    }

    // ---- store (B, 2, NY, NX) ----
    float* o_re = out + ((size_t)(b * 2 + 0) * NY + y) * NX + x0;
    float* o_im = out + ((size_t)(b * 2 + 1) * NY + y) * NX + x0;
    *(float4*)(o_re)     = ar0;
    *(float4*)(o_re + 4) = ar1;
    *(float4*)(o_im)     = ai0;
    *(float4*)(o_im + 4) = ai1;
}

extern "C" void kernel_launch(void* const* d_in, const int* in_sizes, int n_in,
                              void* d_out, int out_size, void* d_ws, size_t ws_size,
                              hipStream_t stream) {
    const float* Rq_re    = (const float*)d_in[0];
    const float* Rq_im    = (const float*)d_in[1];
    const float* Dq_re    = (const float*)d_in[2];
    const float* Dq_im    = (const float*)d_in[3];
    const float* cache_re = (const float*)d_in[4];
    const float* cache_im = (const float*)d_in[5];
    const float* filt     = (const float*)d_in[6];
    float* out = (float*)d_out;

    const int B = in_sizes[0] / (NY * NX);   // = 8

    dim3 block(256);
    dim3 grid(NY / 4, B);
    momentum_kernel<<<grid, block, 0, stream>>>(Rq_re, Rq_im, Dq_re, Dq_im,
                                                cache_re, cache_im, filt, out);
}